// Round 1
// 103.194 us; speedup vs baseline: 1.0585x; 1.0585x over previous
//
#include <hip/hip_runtime.h>
#include <math.h>

#define LENGTH   8192
#define CHANNELS 512
#define NSTATE   64
#define TCHUNK   64
#define NCHUNK   (LENGTH / TCHUNK)            /* 128 */
#define LOG2E    1.4426950408889634f
#define DT       (1.0f / 4096.0f)

// Math (rescaled state h' = h/Bbar):  h'_t = Abar*h'_{t-1} + x_t ; y = sum_n CB_n h'_n
//   Abar_n = exp(A_n*dt), A_n = -exp(logA_n), CB_n = C_n*Bbar_n, Bbar = expm1(A*dt)*B/A
// Chunked (T=64), DIRECT-SIMULATION form (no Toeplitz matmuls, no LDS operand tiles):
//   pass1: E_k[n][c]  = state after running chunk k from h=0      (32 states/thread in VGPR)
//   pass2: carry[k]   = Abar^T*carry[k-1] + E[k-1], carry[0]=0    (serial over k, in place)
//   pass3: run chunk k from h=carry_k, emit y_t = sum_n CB_n h_n  (64 FMA/step, SGPR consts)
// SCRATCH = d_out. E is exactly LENGTH*CHANNELS*4 = 16 MB = |y|. Pass3 block (k,ctile)
// reads carries from [k*32768 + n*512 + c] and writes y to [k*32768 + t*512 + c]: the same
// region, same block; carry loads are consumed into registers before the t-loop, y stores
// happen in the epilogue after __syncthreads(). No cross-block overlap (disjoint k/ctile).
// => d_ws is never touched (its 268 MB re-poison fill was the largest dispatch in the trace).

// Broadcast lane `lane`'s value to all lanes -> lands in an SGPR.
__device__ __forceinline__ float lane_bcast_f(float v, int lane) {
    return __int_as_float(__builtin_amdgcn_readlane(__float_as_int(v), lane));
}

// ---------------------------------------------------------------------------
// Pass 1: thread = (chunk k, channel c, state-half). 32 h-states in VGPRs,
// Abar in SGPRs (computed once across lanes, readlane-broadcast). No LDS.
// grid = 128 chunks * 4 ctiles(128ch), block = 256 (= 128 c * 2 halves).
// ---------------------------------------------------------------------------
__global__ __launch_bounds__(256, 2) void k_pass1(const float* __restrict__ x,
                                                  const float* __restrict__ logA,
                                                  float* __restrict__ E) {
    int tid  = threadIdx.x;
    int k    = blockIdx.x >> 2;
    int c    = ((blockIdx.x & 3) << 7) + (tid & 127);
    int half = tid >> 7;                       // wave-uniform (waves 0,1 -> 0; 2,3 -> 1)
    int lane = tid & 63;

    // lane L computes Abar for n = half*32 + (L&31); broadcast lanes 0..31 to SGPRs.
    int   nme = (half << 5) + (lane & 31);
    float Av  = -expf(logA[nme]);
    float abv = exp2f(Av * DT * LOG2E);

    float a[32];
    #pragma unroll
    for (int i = 0; i < 32; ++i) a[i] = lane_bcast_f(abv, i);

    float h[32];
    #pragma unroll
    for (int i = 0; i < 32; ++i) h[i] = 0.f;

    const float* xp = x + (size_t)k * TCHUNK * CHANNELS + c;
    float xv = xp[0];
    #pragma unroll 7
    for (int t = 0; t < TCHUNK - 1; ++t) {     // 63 iters, prefetch next row
        float xn = xp[(size_t)(t + 1) * CHANNELS];
        #pragma unroll
        for (int i = 0; i < 32; ++i) h[i] = fmaf(a[i], h[i], xv);
        xv = xn;
    }
    #pragma unroll
    for (int i = 0; i < 32; ++i) h[i] = fmaf(a[i], h[i], xv);

    float* Ep = E + ((size_t)k * NSTATE + (half << 5)) * CHANNELS + c;
    #pragma unroll
    for (int i = 0; i < 32; ++i) Ep[(size_t)i * CHANNELS] = h[i];
}

// ---------------------------------------------------------------------------
// Pass 2: per (state n, channel c): serial carry scan over chunks, in place,
// group-16 double-buffered. n is block-uniform -> aT scalar. (unchanged)
// ---------------------------------------------------------------------------
#define G2 16
__global__ __launch_bounds__(64, 1) void k_pass2(float* __restrict__ W,
                                                 const float* __restrict__ logA) {
    int gtid = blockIdx.x * 64 + threadIdx.x;
    int c = gtid & (CHANNELS - 1);
    int n = gtid >> 9;
    float A  = -expf(logA[n]);
    float aT = exp2f(A * (64.0f * DT) * LOG2E);   // Abar^TCHUNK
    float* p = W + (size_t)n * CHANNELS + c;
    const size_t S = (size_t)NSTATE * CHANNELS;

    float e[2][G2];
    #pragma unroll
    for (int j = 0; j < G2; ++j) e[0][j] = p[(size_t)j * S];

    float hc = 0.f;
    #pragma unroll
    for (int k0 = 0; k0 < NCHUNK; k0 += G2) {
        const int cur = (k0 / G2) & 1;
        const int nxt = cur ^ 1;
        if (k0 + G2 < NCHUNK) {
            #pragma unroll
            for (int j = 0; j < G2; ++j) e[nxt][j] = p[(size_t)(k0 + G2 + j) * S];
        }
        #pragma unroll
        for (int j = 0; j < G2; ++j) {
            p[(size_t)(k0 + j) * S] = hc;
            hc = fmaf(aT, hc, e[cur][j]);
        }
    }
}

// ---------------------------------------------------------------------------
// Pass 3: thread = (chunk k, channel c, state-half). h init = carry (from W,
// which aliases y), 64 steps of {h = Abar*h + x ; y_t += CB*h}. Abar and CB
// in SGPRs. Per-step one ds_write_b32 of the half's y partial; epilogue adds
// the two halves from LDS and stores y as float4.
// ---------------------------------------------------------------------------
__global__ __launch_bounds__(256, 2) void k_pass3(const float* __restrict__ x,
                                                  const float* __restrict__ logA,
                                                  const float* __restrict__ Bv,
                                                  const float* __restrict__ Cv,
                                                  const float* __restrict__ W,
                                                  float* __restrict__ y) {
    __shared__ float yp[2][TCHUNK][128];       // 64 KB -> 2 blocks/CU
    int tid  = threadIdx.x;
    int k    = blockIdx.x >> 2;
    int c0g  = (blockIdx.x & 3) << 7;
    int cl   = tid & 127;
    int c    = c0g + cl;
    int half = tid >> 7;                       // wave-uniform
    int lane = tid & 63;

    int   nme  = (half << 5) + (lane & 31);
    float Av   = -expf(logA[nme]);
    float abv  = exp2f(Av * DT * LOG2E);
    float Bbar = expm1f(Av * DT) * Bv[nme] / Av;
    float cbv  = Cv[nme] * Bbar;

    float a[32], cb[32];
    #pragma unroll
    for (int i = 0; i < 32; ++i) {
        a[i]  = lane_bcast_f(abv, i);
        cb[i] = lane_bcast_f(cbv, i);
    }

    // h init = carry_k (reads alias the y region this block will write later;
    // all loads are consumed into registers before the first y store)
    const float* Wp = W + ((size_t)k * NSTATE + (half << 5)) * CHANNELS + c;
    float h[32];
    #pragma unroll
    for (int i = 0; i < 32; ++i) h[i] = Wp[(size_t)i * CHANNELS];

    const float* xp = x + (size_t)k * TCHUNK * CHANNELS + c;
    float* ypb = &yp[half][0][cl];

    float xv = xp[0];
    #pragma unroll 3
    for (int t = 0; t < TCHUNK - 1; ++t) {     // 63 iters, prefetch next row
        float xn = xp[(size_t)(t + 1) * CHANNELS];
        float y0 = 0.f, y1 = 0.f, y2 = 0.f, y3 = 0.f;
        #pragma unroll
        for (int i = 0; i < 32; i += 4) {
            h[i]   = fmaf(a[i],   h[i],   xv);  y0 = fmaf(cb[i],   h[i],   y0);
            h[i+1] = fmaf(a[i+1], h[i+1], xv);  y1 = fmaf(cb[i+1], h[i+1], y1);
            h[i+2] = fmaf(a[i+2], h[i+2], xv);  y2 = fmaf(cb[i+2], h[i+2], y2);
            h[i+3] = fmaf(a[i+3], h[i+3], xv);  y3 = fmaf(cb[i+3], h[i+3], y3);
        }
        ypb[t * 128] = (y0 + y1) + (y2 + y3);
        xv = xn;
    }
    {   // final step t = 63
        float y0 = 0.f, y1 = 0.f, y2 = 0.f, y3 = 0.f;
        #pragma unroll
        for (int i = 0; i < 32; i += 4) {
            h[i]   = fmaf(a[i],   h[i],   xv);  y0 = fmaf(cb[i],   h[i],   y0);
            h[i+1] = fmaf(a[i+1], h[i+1], xv);  y1 = fmaf(cb[i+1], h[i+1], y1);
            h[i+2] = fmaf(a[i+2], h[i+2], xv);  y2 = fmaf(cb[i+2], h[i+2], y2);
            h[i+3] = fmaf(a[i+3], h[i+3], xv);  y3 = fmaf(cb[i+3], h[i+3], y3);
        }
        ypb[(TCHUNK - 1) * 128] = (y0 + y1) + (y2 + y3);
    }
    __syncthreads();

    // epilogue: y[k*64+t][c0g+cq..cq+3] = yp[0][t][cq..] + yp[1][t][cq..]
    float* yg = y + (size_t)k * TCHUNK * CHANNELS + c0g;
    #pragma unroll
    for (int i = 0; i < 8; ++i) {
        int idx = (i << 8) + tid;              // 0..2047 float4 slots (64 t * 32 quads)
        int t   = idx >> 5;
        int cq  = (idx & 31) << 2;
        float4 v0 = *(const float4*)&yp[0][t][cq];
        float4 v1 = *(const float4*)&yp[1][t][cq];
        *(float4*)(yg + (size_t)t * CHANNELS + cq) =
            make_float4(v0.x + v1.x, v0.y + v1.y, v0.z + v1.z, v0.w + v1.w);
    }
}

extern "C" void kernel_launch(void* const* d_in, const int* in_sizes, int n_in,
                              void* d_out, int out_size, void* d_ws, size_t ws_size,
                              hipStream_t stream) {
    const float* x    = (const float*)d_in[0];
    const float* logA = (const float*)d_in[1];
    const float* B    = (const float*)d_in[2];
    const float* C    = (const float*)d_in[3];
    float* yout = (float*)d_out;

    // d_out doubles as the E/carry buffer (exactly 16 MB, aliasing proven safe:
    // pass3 reads carries of region k before writing y of region k, same block).
    float* W = yout;
    (void)d_ws; (void)ws_size;

    k_pass1<<<NCHUNK * 4, 256, 0, stream>>>(x, logA, W);
    k_pass2<<<(NSTATE * CHANNELS) / 64, 64, 0, stream>>>(W, logA);
    k_pass3<<<NCHUNK * 4, 256, 0, stream>>>(x, logA, B, C, W, yout);
}

// Round 2
// 99.287 us; speedup vs baseline: 1.1001x; 1.0393x over previous
//
#include <hip/hip_runtime.h>
#include <math.h>

#define LENGTH   8192
#define CHANNELS 512
#define NSTATE   64
#define TCHUNK   128
#define NCHUNK   (LENGTH / TCHUNK)            /* 64 */
#define CTILE    64
#define NQ       4                            /* state quarters, 16 states each */
#define TTILE    32
#define E_ELEMS  (NCHUNK * NSTATE * CHANNELS) /* 8 MB: E / carry buffer in ws */
#define LOG2E    1.4426950408889634f
#define DT       (1.0f / 4096.0f)

// Math (rescaled state h' = h/Bbar):  h'_t = Abar*h'_{t-1} + x_t ; y = sum_n CB_n h'_n
//   Abar_n = exp(A_n*dt), A_n = -exp(logA_n), CB_n = C_n*Bbar_n, Bbar = expm1(A*dt)*B/A
// Chunked (T=128), DIRECT-SIMULATION form:
//   pass1: E_k[n][c] = state after chunk k from h=0   (16 states/thread, Abar in SGPRs)
//   pass2: carry[k]  = Abar^T*carry[k-1] + E[k-1]     (serial over k, in place, in ws)
//   pass3: run chunk k from h=carry_k, y_t = sum_n CB_n h_n  (32 FMA/step/thread)
// T=128 (vs 64) halves E/carry HBM traffic (64->32 MB). E lives in d_ws: round 1
// proved the 268 MB ws poison-fill happens whether or not we touch ws, so using 8 MB
// of it is free (and out-buffer aliasing is no longer safe since |E| != |y|).
// x is staged once per block into LDS (32 KB) instead of 4 redundant global streams.

// Broadcast lane `lane`'s value to all lanes -> lands in an SGPR.
__device__ __forceinline__ float lane_bcast_f(float v, int lane) {
    return __int_as_float(__builtin_amdgcn_readlane(__float_as_int(v), lane));
}

// ---------------------------------------------------------------------------
// Pass 1: block = (chunk k, 64-ch tile); thread = (channel cl, state-quarter q).
// 16 h-states in VGPRs, Abar in SGPRs. x staged in LDS. grid = 64*8 = 512.
// ---------------------------------------------------------------------------
__global__ __launch_bounds__(256, 4) void k_pass1(const float* __restrict__ x,
                                                  const float* __restrict__ logA,
                                                  float* __restrict__ E) {
    __shared__ float Xl[TCHUNK * CTILE];   // 32 KB
    int tid = threadIdx.x;
    int k   = blockIdx.x >> 3;
    int ct  = blockIdx.x & 7;
    int cl  = tid & 63;
    int q   = tid >> 6;                    // wave-uniform
    int c0g = ct * CTILE;

    const float* xsrc = x + (size_t)k * TCHUNK * CHANNELS + c0g;
    #pragma unroll
    for (int i = 0; i < 8; ++i) {
        int idx = (i << 8) + tid;          // 0..2047 float4 slots (128 t * 16 quads)
        int t   = idx >> 4;
        int cq  = (idx & 15) << 2;
        *(float4*)&Xl[t * CTILE + cq] = *(const float4*)(xsrc + (size_t)t * CHANNELS + cq);
    }

    int   nme = (q << 4) + (cl & 15);      // lane L computes Abar for n = q*16 + (L&15)
    float Av  = -expf(logA[nme]);
    float abv = exp2f(Av * DT * LOG2E);
    float a[16];
    #pragma unroll
    for (int i = 0; i < 16; ++i) a[i] = lane_bcast_f(abv, i);

    float h[16];
    #pragma unroll
    for (int i = 0; i < 16; ++i) h[i] = 0.f;

    __syncthreads();

    #pragma unroll 8
    for (int t = 0; t < TCHUNK; ++t) {
        float xv = Xl[t * CTILE + cl];
        #pragma unroll
        for (int i = 0; i < 16; ++i) h[i] = fmaf(a[i], h[i], xv);
    }

    float* Ep = E + ((size_t)k * NSTATE + (q << 4)) * CHANNELS + c0g + cl;
    #pragma unroll
    for (int i = 0; i < 16; ++i) Ep[(size_t)i * CHANNELS] = h[i];
}

// ---------------------------------------------------------------------------
// Pass 2: per (state n, channel c): serial carry scan over 64 chunks, in place,
// group-16 double-buffered. n is block-uniform within a wave -> aT scalar-ish.
// ---------------------------------------------------------------------------
#define G2 16
__global__ __launch_bounds__(256, 1) void k_pass2(float* __restrict__ W,
                                                  const float* __restrict__ logA) {
    int gtid = blockIdx.x * 256 + threadIdx.x;
    int c = gtid & (CHANNELS - 1);
    int n = gtid >> 9;
    float A  = -expf(logA[n]);
    float aT = exp2f(A * ((float)TCHUNK * DT) * LOG2E);   // Abar^TCHUNK
    float* p = W + (size_t)n * CHANNELS + c;
    const size_t S = (size_t)NSTATE * CHANNELS;

    float e[2][G2];
    #pragma unroll
    for (int j = 0; j < G2; ++j) e[0][j] = p[(size_t)j * S];

    float hc = 0.f;
    #pragma unroll
    for (int k0 = 0; k0 < NCHUNK; k0 += G2) {
        const int cur = (k0 / G2) & 1;
        const int nxt = cur ^ 1;
        if (k0 + G2 < NCHUNK) {
            #pragma unroll
            for (int j = 0; j < G2; ++j) e[nxt][j] = p[(size_t)(k0 + G2 + j) * S];
        }
        #pragma unroll
        for (int j = 0; j < G2; ++j) {
            p[(size_t)(k0 + j) * S] = hc;
            hc = fmaf(aT, hc, e[cur][j]);
        }
    }
}

// ---------------------------------------------------------------------------
// Pass 3: block = (chunk k, 64-ch tile); thread = (cl, quarter q). h init =
// carry_k from ws; 128 steps of {h = a*h + x ; y_t += cb*h}. y-partials of the
// 4 quarters combined via a 32-row LDS tile, flushed 4x as float4 stores.
// LDS = 32 (Xl) + 32 (yp) = 64 KB -> 2 blocks/CU.
// ---------------------------------------------------------------------------
__global__ __launch_bounds__(256, 2) void k_pass3(const float* __restrict__ x,
                                                  const float* __restrict__ logA,
                                                  const float* __restrict__ Bv,
                                                  const float* __restrict__ Cv,
                                                  const float* __restrict__ W,
                                                  float* __restrict__ y) {
    __shared__ float Xl[TCHUNK * CTILE];       // 32 KB
    __shared__ float yp[NQ][TTILE][CTILE];     // 32 KB
    int tid = threadIdx.x;
    int k   = blockIdx.x >> 3;
    int ct  = blockIdx.x & 7;
    int cl  = tid & 63;
    int q   = tid >> 6;                        // wave-uniform
    int c0g = ct * CTILE;

    const float* xsrc = x + (size_t)k * TCHUNK * CHANNELS + c0g;
    #pragma unroll
    for (int i = 0; i < 8; ++i) {
        int idx = (i << 8) + tid;
        int t   = idx >> 4;
        int cq  = (idx & 15) << 2;
        *(float4*)&Xl[t * CTILE + cq] = *(const float4*)(xsrc + (size_t)t * CHANNELS + cq);
    }

    int   nme  = (q << 4) + (cl & 15);
    float Av   = -expf(logA[nme]);
    float abv  = exp2f(Av * DT * LOG2E);
    float Bbar = expm1f(Av * DT) * Bv[nme] / Av;
    float cbv  = Cv[nme] * Bbar;

    float a[16], cb[16];
    #pragma unroll
    for (int i = 0; i < 16; ++i) {
        a[i]  = lane_bcast_f(abv, i);
        cb[i] = lane_bcast_f(cbv, i);
    }

    const float* Wp = W + ((size_t)k * NSTATE + (q << 4)) * CHANNELS + c0g + cl;
    float h[16];
    #pragma unroll
    for (int i = 0; i < 16; ++i) h[i] = Wp[(size_t)i * CHANNELS];

    __syncthreads();

    float* yg = y + (size_t)k * TCHUNK * CHANNELS + c0g;
    #pragma unroll
    for (int tt = 0; tt < TCHUNK / TTILE; ++tt) {
        #pragma unroll 4
        for (int t = 0; t < TTILE; ++t) {
            float xv = Xl[(tt * TTILE + t) * CTILE + cl];
            float y0 = 0.f, y1 = 0.f, y2 = 0.f, y3 = 0.f;
            #pragma unroll
            for (int i = 0; i < 16; i += 4) {
                h[i]   = fmaf(a[i],   h[i],   xv);  y0 = fmaf(cb[i],   h[i],   y0);
                h[i+1] = fmaf(a[i+1], h[i+1], xv);  y1 = fmaf(cb[i+1], h[i+1], y1);
                h[i+2] = fmaf(a[i+2], h[i+2], xv);  y2 = fmaf(cb[i+2], h[i+2], y2);
                h[i+3] = fmaf(a[i+3], h[i+3], xv);  y3 = fmaf(cb[i+3], h[i+3], y3);
            }
            yp[q][t][cl] = (y0 + y1) + (y2 + y3);
        }
        __syncthreads();
        #pragma unroll
        for (int r = 0; r < 2; ++r) {
            int idx = (r << 8) + tid;          // 0..511 float4 slots (32 t * 16 quads)
            int t   = idx >> 4;
            int cq  = (idx & 15) << 2;
            float4 v0 = *(const float4*)&yp[0][t][cq];
            float4 v1 = *(const float4*)&yp[1][t][cq];
            float4 v2 = *(const float4*)&yp[2][t][cq];
            float4 v3 = *(const float4*)&yp[3][t][cq];
            *(float4*)(yg + (size_t)(tt * TTILE + t) * CHANNELS + cq) =
                make_float4((v0.x + v1.x) + (v2.x + v3.x),
                            (v0.y + v1.y) + (v2.y + v3.y),
                            (v0.z + v1.z) + (v2.z + v3.z),
                            (v0.w + v1.w) + (v2.w + v3.w));
        }
        __syncthreads();
    }
}

// ---------------------------------------------------------------------------
// Fallback (only if ws is too small): one thread per channel, full scan.
// ---------------------------------------------------------------------------
__global__ __launch_bounds__(256) void k_fallback(const float* __restrict__ x,
                                                  const float* __restrict__ logA,
                                                  const float* __restrict__ B,
                                                  const float* __restrict__ C,
                                                  float* __restrict__ y) {
    int c = blockIdx.x * blockDim.x + threadIdx.x;
    if (c >= CHANNELS) return;
    float Abar[NSTATE], CB[NSTATE], h[NSTATE];
    for (int n = 0; n < NSTATE; ++n) {
        float A    = -expf(logA[n]);
        float ab   = exp2f(A * DT * LOG2E);
        float Bbar = expm1f(A * DT) * B[n] / A;
        Abar[n] = ab;
        CB[n]   = C[n] * Bbar;
        h[n]    = 0.f;
    }
    for (int t = 0; t < LENGTH; ++t) {
        float xv = x[(size_t)t * CHANNELS + c];
        float acc = 0.f;
        for (int n = 0; n < NSTATE; ++n) {
            h[n] = fmaf(Abar[n], h[n], xv);
            acc  = fmaf(CB[n], h[n], acc);
        }
        y[(size_t)t * CHANNELS + c] = acc;
    }
}

extern "C" void kernel_launch(void* const* d_in, const int* in_sizes, int n_in,
                              void* d_out, int out_size, void* d_ws, size_t ws_size,
                              hipStream_t stream) {
    const float* x    = (const float*)d_in[0];
    const float* logA = (const float*)d_in[1];
    const float* B    = (const float*)d_in[2];
    const float* C    = (const float*)d_in[3];
    float* yout = (float*)d_out;

    if (ws_size < (size_t)E_ELEMS * sizeof(float)) {
        k_fallback<<<(CHANNELS + 255) / 256, 256, 0, stream>>>(x, logA, B, C, yout);
        return;
    }
    float* W = (float*)d_ws;   // E / carry buffer, 8 MB (ws poison happens regardless)

    k_pass1<<<NCHUNK * 8, 256, 0, stream>>>(x, logA, W);
    k_pass2<<<(NSTATE * CHANNELS) / 256, 256, 0, stream>>>(W, logA);
    k_pass3<<<NCHUNK * 8, 256, 0, stream>>>(x, logA, B, C, W, yout);
}